// Round 2
// baseline (173.793 us; speedup 1.0000x reference)
//
#include <hip/hip_runtime.h>

#define BB 16
#define NN 1024
#define CC 64

typedef __attribute__((ext_vector_type(8))) short short8;
typedef __attribute__((ext_vector_type(4))) float f32x4;
typedef __attribute__((ext_vector_type(4))) int   i32x4;

__device__ __forceinline__ unsigned short bf16_rne(float f) {
    unsigned u = __float_as_uint(f);
    u += 0x7fffu + ((u >> 16) & 1u);
    return (unsigned short)(u >> 16);
}

// ---------------- Kernel 1: xw = x@W_rel -> bf16 swizzled (B-frag order);
//                  out = x@W_root + b_rel (fp32) ----------------
extern "C" __global__ __launch_bounds__(256)
void precompute(const float* __restrict__ x, const float* __restrict__ W_rel,
                const float* __restrict__ W_root, const float* __restrict__ b_rel,
                unsigned short* __restrict__ xw_sw, float* __restrict__ out)
{
    __shared__ float wrel_s[64 * 64];
    __shared__ float wroot_s[64 * 64];
    __shared__ float x_s[16 * 68];

    const int t = threadIdx.x;
    #pragma unroll
    for (int k = 0; k < 4; ++k) {
        int i4 = t + 256 * k;
        ((float4*)wrel_s)[i4]  = ((const float4*)W_rel)[i4];
        ((float4*)wroot_s)[i4] = ((const float4*)W_root)[i4];
    }
    const int row0 = blockIdx.x * 16;
    {
        int r = t >> 4, c4 = t & 15;
        *(float4*)(x_s + r * 68 + c4 * 4) = ((const float4*)(x + (size_t)(row0 + r) * CC))[c4];
    }
    __syncthreads();

    const int c4 = t & 15;
    const int r  = t >> 4;
    float aw0 = 0.f, aw1 = 0.f, aw2 = 0.f, aw3 = 0.f;
    float ar0 = 0.f, ar1 = 0.f, ar2 = 0.f, ar3 = 0.f;
    const float* xrow = x_s + r * 68;
    #pragma unroll 8
    for (int k = 0; k < 64; ++k) {
        float xv = xrow[k];
        float4 wv = ((const float4*)(wrel_s  + k * 64))[c4];
        float4 rv = ((const float4*)(wroot_s + k * 64))[c4];
        aw0 += xv * wv.x; aw1 += xv * wv.y; aw2 += xv * wv.z; aw3 += xv * wv.w;
        ar0 += xv * rv.x; ar1 += xv * rv.y; ar2 += xv * rv.z; ar3 += xv * rv.w;
    }

    const int row_g = row0 + r;
    {
        const float4 bv = ((const float4*)b_rel)[c4];
        ((float4*)out)[(size_t)row_g * 16 + c4] =
            make_float4(ar0 + bv.x, ar1 + bv.y, ar2 + bv.z, ar3 + bv.w);
    }
    {
        const int b = row_g >> 10;
        const int k = row_g & 1023;
        const int kb = k >> 5;
        const int qk = (k >> 3) & 3;
        const int j  = k & 7;
        const int c  = 4 * c4;
        const int n0 = c >> 4;
        const int n  = c & 15;
        size_t off = ((size_t)b << 16) + (size_t)((kb * 4 + n0) << 9)
                   + (size_t)((n + (qk << 4)) << 3) + j;
        xw_sw[off]      = bf16_rne(aw0);
        xw_sw[off + 8]  = bf16_rne(aw1);
        xw_sw[off + 16] = bf16_rne(aw2);
        xw_sw[off + 24] = bf16_rne(aw3);
    }
}

// ---------------- Kernel 2: out += (adj .* w_edge[ea]) @ xw  (bf16 MFMA) ----
// v3: contiguous-streaming restructure (v1/v2 identical perf proved the
// bottleneck was the 16B-granule scatter of chunked A-frag DMA, not the
// pipeline). One block per (b, 32-row tile), FULL K:
//   Phase A: stream the block's adj+ea regions (contiguous 128KB each;
//     thread t owns k in [4t,4t+4) of every row -> every wave instruction is
//     a 1KB sequential read; 8-deep register pipeline = 16 loads in flight),
//     convert to bf16 adj*wsel(ea) in VGPRs, write the 64KB A-tile to LDS in
//     MFMA A-frag layout with XOR swizzle (m ^= ((kb&3)<<2)|q) so the
//     uniform-row ds_write_b64 drops from 32-way to ~4-way conflicts.
//   One barrier.
//   Phase B: 32 MFMA k-steps from LDS (conflict-free b128 A reads) + xw
//     B-frags from global (2MB, L2-resident).
// Exclusive row ownership -> plain fp32 RMW epilogue, no atomics.
// grid = B * (N/32) = 512 blocks x 256 threads; 64KB LDS -> 2 blk/CU, all
// co-resident.
extern "C" __global__ __launch_bounds__(256, 2)
void gnn_mfma(const float* __restrict__ adj, const int* __restrict__ ea,
              const float* __restrict__ w_edge,
              const unsigned short* __restrict__ xw_sw,
              float* __restrict__ out)
{
    __shared__ __align__(16) char lds[65536];

    const int t     = threadIdx.x;
    const int mtile = blockIdx.x & 31;
    const int b     = blockIdx.x >> 5;
    const int row0  = mtile << 5;

    // cubic through (e, w_edge[e]) for e=0..3 — exact branchless gather
    const float w0 = w_edge[0], w1 = w_edge[1], w2 = w_edge[2], w3 = w_edge[3];
    const float d1 = w1 - w0;
    const float d2 = w2 - 2.f * w1 + w0;
    const float d3 = w3 - 3.f * w2 + 3.f * w1 - w0;
    const float c3 = d3 * (1.f / 6.f);
    const float c2 = 0.5f * d2 - 0.5f * d3;
    const float c1 = d1 - 0.5f * d2 + (1.f / 3.f) * d3;
    const float c0 = w0;

#define WSEL(ev) __builtin_fmaf(__builtin_fmaf(__builtin_fmaf(c3, (float)(ev), c2), (float)(ev), c1), (float)(ev), c0)

    // ---------------- Phase A: contiguous stream + convert + LDS-frag write ---
    // Thread t owns k = 4t..4t+3 (so kb = t>>3, q = (t>>1)&3, half = t&1 are
    // thread-constant); iteration i = row. Wave instruction i covers floats
    // [i*1024 + w*256, +256) = 1KB contiguous; whole block = 128KB sequential.
    const size_t gbase = ((size_t)b << 20) + ((size_t)row0 << 10);
    const float4* A4 = (const float4*)(adj + gbase);
    const i32x4*  E4 = (const i32x4*)(ea + gbase);

    const int kb_t   = t >> 3;
    const int q_t    = (t >> 1) & 3;
    const int X_t    = ((kb_t & 3) << 2) | q_t;
    const int wbase  = (kb_t << 10) + (q_t << 8) + ((t & 1) << 3);

    float4 aa[8]; i32x4 ee[8];
    #pragma unroll
    for (int d = 0; d < 8; ++d) { aa[d] = A4[d * 256 + t]; ee[d] = E4[d * 256 + t]; }

    #pragma unroll
    for (int i = 0; i < 32; ++i) {
        float4 av = aa[i & 7];
        i32x4  ev = ee[i & 7];
        if (i < 24) {                       // prefetch row i+8 (compile-time guard)
            aa[i & 7] = A4[(i + 8) * 256 + t];
            ee[i & 7] = E4[(i + 8) * 256 + t];
        }
        float p0 = av.x * WSEL(ev[0]);
        float p1 = av.y * WSEL(ev[1]);
        float p2 = av.z * WSEL(ev[2]);
        float p3 = av.w * WSEL(ev[3]);
        unsigned u0 = __builtin_amdgcn_perm(__float_as_uint(p1), __float_as_uint(p0), 0x07060302u);
        unsigned u1 = __builtin_amdgcn_perm(__float_as_uint(p3), __float_as_uint(p2), 0x07060302u);
        const int m  = i & 15;
        const int mh = i >> 4;
        // frag(mh,kb) 1KB; lane slot (q*16 + (m^X)) * 16B; half*8B
        const int addr = (mh << 15) + wbase + ((m ^ X_t) << 4);
        *(uint2*)(lds + addr) = make_uint2(u0, u1);
    }
    __syncthreads();

    // ---------------- Phase B: MFMA from LDS A-frags + global xw B-frags ------
    const int w    = t >> 6;
    const int lane = t & 63;
    const int m    = lane & 15;
    const int q    = lane >> 4;
    const int wm   = w >> 1;            // 16-row half
    const int wn   = w & 1;             // 32-col half

    const unsigned short* xwb = xw_sw + ((size_t)b << 16)
                              + ((size_t)(wn * 2) << 9) + ((size_t)lane << 3);
    const char* abase = lds + (wm << 15) + (q << 8);

    f32x4 acc0 = {0.f, 0.f, 0.f, 0.f};
    f32x4 acc1 = acc0;

    #pragma unroll
    for (int kb = 0; kb < 32; ++kb) {
        const int X = ((kb & 3) << 2) | q;
        short8 af = *(const short8*)(abase + (kb << 10) + ((m ^ X) << 4));
        const unsigned short* xq = xwb + ((size_t)kb << 11);
        short8 bf0 = *(const short8*)(xq);
        short8 bf1 = *(const short8*)(xq + 512);
        acc0 = __builtin_amdgcn_mfma_f32_16x16x32_bf16(af, bf0, acc0, 0, 0, 0);
        acc1 = __builtin_amdgcn_mfma_f32_16x16x32_bf16(af, bf1, acc1, 0, 0, 0);
    }
#undef WSEL

    // ---------------- epilogue: exclusive rows -> plain RMW, no atomics ------
    const size_t R0 = ((size_t)b << 10) + row0 + (wm << 4) + (q << 2);
    float* ob = out + (R0 << 6) + (wn << 5) + m;
    #pragma unroll
    for (int rg = 0; rg < 4; ++rg) {
        ob[rg * 64]      += acc0[rg];
        ob[rg * 64 + 16] += acc1[rg];
    }
}

extern "C" void kernel_launch(void* const* d_in, const int* in_sizes, int n_in,
                              void* d_out, int out_size, void* d_ws, size_t ws_size,
                              hipStream_t stream) {
    const float* x      = (const float*)d_in[0];
    const float* adj    = (const float*)d_in[1];
    const int*   ea     = (const int*)  d_in[2];
    const float* W_rel  = (const float*)d_in[3];
    const float* b_rel  = (const float*)d_in[4];
    const float* W_root = (const float*)d_in[5];
    const float* w_edge = (const float*)d_in[6];
    float* out = (float*)d_out;

    unsigned short* xw_sw = (unsigned short*)d_ws;   // B*N*C bf16 = 2 MiB

    precompute<<<BB * NN / 16, 256, 0, stream>>>(x, W_rel, W_root, b_rel, xw_sw, out);
    gnn_mfma<<<BB * (NN / 32), 256, 0, stream>>>(adj, ea, w_edge, xw_sw, out);
}

// Round 3
// 164.885 us; speedup vs baseline: 1.0540x; 1.0540x over previous
//
#include <hip/hip_runtime.h>

#define BB 16
#define NN 1024
#define CC 64

typedef __attribute__((ext_vector_type(8))) short short8;
typedef __attribute__((ext_vector_type(4))) float f32x4;
typedef __attribute__((ext_vector_type(4))) int   i32x4;

__device__ __forceinline__ unsigned short bf16_rne(float f) {
    unsigned u = __float_as_uint(f);
    u += 0x7fffu + ((u >> 16) & 1u);
    return (unsigned short)(u >> 16);
}

// ---------------- Kernel 1: xw = x@W_rel -> bf16 swizzled (B-frag order);
//                  out = x@W_root + b_rel (fp32) ----------------
extern "C" __global__ __launch_bounds__(256)
void precompute(const float* __restrict__ x, const float* __restrict__ W_rel,
                const float* __restrict__ W_root, const float* __restrict__ b_rel,
                unsigned short* __restrict__ xw_sw, float* __restrict__ out)
{
    __shared__ float wrel_s[64 * 64];
    __shared__ float wroot_s[64 * 64];
    __shared__ float x_s[16 * 68];

    const int t = threadIdx.x;
    #pragma unroll
    for (int k = 0; k < 4; ++k) {
        int i4 = t + 256 * k;
        ((float4*)wrel_s)[i4]  = ((const float4*)W_rel)[i4];
        ((float4*)wroot_s)[i4] = ((const float4*)W_root)[i4];
    }
    const int row0 = blockIdx.x * 16;
    {
        int r = t >> 4, c4 = t & 15;
        *(float4*)(x_s + r * 68 + c4 * 4) = ((const float4*)(x + (size_t)(row0 + r) * CC))[c4];
    }
    __syncthreads();

    const int c4 = t & 15;
    const int r  = t >> 4;
    float aw0 = 0.f, aw1 = 0.f, aw2 = 0.f, aw3 = 0.f;
    float ar0 = 0.f, ar1 = 0.f, ar2 = 0.f, ar3 = 0.f;
    const float* xrow = x_s + r * 68;
    #pragma unroll 8
    for (int k = 0; k < 64; ++k) {
        float xv = xrow[k];
        float4 wv = ((const float4*)(wrel_s  + k * 64))[c4];
        float4 rv = ((const float4*)(wroot_s + k * 64))[c4];
        aw0 += xv * wv.x; aw1 += xv * wv.y; aw2 += xv * wv.z; aw3 += xv * wv.w;
        ar0 += xv * rv.x; ar1 += xv * rv.y; ar2 += xv * rv.z; ar3 += xv * rv.w;
    }

    const int row_g = row0 + r;
    {
        const float4 bv = ((const float4*)b_rel)[c4];
        ((float4*)out)[(size_t)row_g * 16 + c4] =
            make_float4(ar0 + bv.x, ar1 + bv.y, ar2 + bv.z, ar3 + bv.w);
    }
    {
        const int b = row_g >> 10;
        const int k = row_g & 1023;
        const int kb = k >> 5;
        const int qk = (k >> 3) & 3;
        const int j  = k & 7;
        const int c  = 4 * c4;
        const int n0 = c >> 4;
        const int n  = c & 15;
        size_t off = ((size_t)b << 16) + (size_t)((kb * 4 + n0) << 9)
                   + (size_t)((n + (qk << 4)) << 3) + j;
        xw_sw[off]      = bf16_rne(aw0);
        xw_sw[off + 8]  = bf16_rne(aw1);
        xw_sw[off + 16] = bf16_rne(aw2);
        xw_sw[off + 24] = bf16_rne(aw3);
    }
}

// ---------------- Kernel 2: out += (adj .* w_edge[ea]) @ xw  (bf16 MFMA) ----
// v4: three schedules (v1 DMA-chunked, v2 counted-vmcnt, v3 contiguous reg-
// pipelined) all pinned at 52us / 2.5TB/s with idle pipes -> cap is in the
// memory system's service of this (partially L3-resident) stream, not in
// request generation. Two levers this round:
//   (1) NONTEMPORAL loads on adj/ea (zero-reuse data): stream policy, bypass
//       the cache-hit path suspected of capping delivery.
//   (2) 16-row blocks: grid 1024, LDS 32KB -> 4-5 blocks/CU (~16-20 waves/CU
//       streaming), better duty cycle (blocks in MFMA phase overlap others'
//       stream phase). No atomics (exclusive 16-row ownership).
// Phase A: thread t owns k in [4t,4t+4) of every row; each wave instruction
//   reads 1KB contiguous; 8-row-deep register pipeline; convert to bf16
//   adj*wsel(ea), write A-frags to LDS with XOR swizzle (m ^= ((kb&3)<<2)|q).
// Phase B: 32 MFMA k-steps; A-frags from LDS (conflict-free b128), xw B-frags
//   from global (2MB, L2-resident, normal cache policy).
extern "C" __global__ __launch_bounds__(256, 4)
void gnn_mfma(const float* __restrict__ adj, const int* __restrict__ ea,
              const float* __restrict__ w_edge,
              const unsigned short* __restrict__ xw_sw,
              float* __restrict__ out)
{
    __shared__ __align__(16) char lds[32768];

    const int t     = threadIdx.x;
    const int mtile = blockIdx.x & 63;
    const int b     = blockIdx.x >> 6;
    const int row0  = mtile << 4;

    // cubic through (e, w_edge[e]) for e=0..3 — exact branchless gather
    const float w0 = w_edge[0], w1 = w_edge[1], w2 = w_edge[2], w3 = w_edge[3];
    const float d1 = w1 - w0;
    const float d2 = w2 - 2.f * w1 + w0;
    const float d3 = w3 - 3.f * w2 + 3.f * w1 - w0;
    const float c3 = d3 * (1.f / 6.f);
    const float c2 = 0.5f * d2 - 0.5f * d3;
    const float c1 = d1 - 0.5f * d2 + (1.f / 3.f) * d3;
    const float c0 = w0;

#define WSEL(ev) __builtin_fmaf(__builtin_fmaf(__builtin_fmaf(c3, (float)(ev), c2), (float)(ev), c1), (float)(ev), c0)

    // ---------------- Phase A: nt-stream + convert + swizzled LDS-frag write --
    const size_t gbase = ((size_t)b << 20) + ((size_t)row0 << 10);
    const f32x4* A4 = (const f32x4*)(adj + gbase);
    const i32x4* E4 = (const i32x4*)(ea + gbase);

    const int kb_t   = t >> 3;
    const int q_t    = (t >> 1) & 3;
    const int X_t    = ((kb_t & 3) << 2) | q_t;
    const int wbase  = (kb_t << 10) + (q_t << 8) + ((t & 1) << 3);

    f32x4 aa[8]; i32x4 ee[8];
    #pragma unroll
    for (int d = 0; d < 8; ++d) {
        aa[d] = __builtin_nontemporal_load(&A4[d * 256 + t]);
        ee[d] = __builtin_nontemporal_load(&E4[d * 256 + t]);
    }

    #pragma unroll
    for (int i = 0; i < 16; ++i) {
        f32x4 av = aa[i & 7];
        i32x4 ev = ee[i & 7];
        if (i < 8) {                        // prefetch row i+8 (compile-time guard)
            aa[i & 7] = __builtin_nontemporal_load(&A4[(i + 8) * 256 + t]);
            ee[i & 7] = __builtin_nontemporal_load(&E4[(i + 8) * 256 + t]);
        }
        float p0 = av[0] * WSEL(ev[0]);
        float p1 = av[1] * WSEL(ev[1]);
        float p2 = av[2] * WSEL(ev[2]);
        float p3 = av[3] * WSEL(ev[3]);
        unsigned u0 = __builtin_amdgcn_perm(__float_as_uint(p1), __float_as_uint(p0), 0x07060302u);
        unsigned u1 = __builtin_amdgcn_perm(__float_as_uint(p3), __float_as_uint(p2), 0x07060302u);
        const int m = i;                    // row within 16-row tile
        const int addr = wbase + ((m ^ X_t) << 4);
        *(uint2*)(lds + addr) = make_uint2(u0, u1);
    }
    __syncthreads();

    // ---------------- Phase B: MFMA from LDS A-frags + global xw B-frags ------
    const int wn   = t >> 6;            // 16-col quarter
    const int lane = t & 63;
    const int m    = lane & 15;
    const int q    = lane >> 4;

    const unsigned short* xwb = xw_sw + ((size_t)b << 16)
                              + ((size_t)wn << 9) + ((size_t)lane << 3);
    const char* abase = lds + (q << 8);

    f32x4 acc0 = {0.f, 0.f, 0.f, 0.f};

    #pragma unroll
    for (int kb = 0; kb < 32; ++kb) {
        const int X = ((kb & 3) << 2) | q;
        short8 af = *(const short8*)(abase + (kb << 10) + ((m ^ X) << 4));
        short8 bf = *(const short8*)(xwb + ((size_t)kb << 11));
        acc0 = __builtin_amdgcn_mfma_f32_16x16x32_bf16(af, bf, acc0, 0, 0, 0);
    }
#undef WSEL

    // ---------------- epilogue: exclusive rows -> plain RMW, no atomics ------
    float* ob = out + ((((size_t)b << 10) + row0 + (q << 2)) << 6) + (wn << 4) + m;
    #pragma unroll
    for (int rg = 0; rg < 4; ++rg) {
        ob[rg * 64] += acc0[rg];
    }
}

extern "C" void kernel_launch(void* const* d_in, const int* in_sizes, int n_in,
                              void* d_out, int out_size, void* d_ws, size_t ws_size,
                              hipStream_t stream) {
    const float* x      = (const float*)d_in[0];
    const float* adj    = (const float*)d_in[1];
    const int*   ea     = (const int*)  d_in[2];
    const float* W_rel  = (const float*)d_in[3];
    const float* b_rel  = (const float*)d_in[4];
    const float* W_root = (const float*)d_in[5];
    const float* w_edge = (const float*)d_in[6];
    float* out = (float*)d_out;

    unsigned short* xw_sw = (unsigned short*)d_ws;   // B*N*C bf16 = 2 MiB

    precompute<<<BB * NN / 16, 256, 0, stream>>>(x, W_rel, W_root, b_rel, xw_sw, out);
    gnn_mfma<<<BB * (NN / 16), 256, 0, stream>>>(adj, ea, w_edge, xw_sw, out);
}